// Round 5
// baseline (241.592 us; speedup 1.0000x reference)
//
#include <hip/hip_runtime.h>
#include <hip/hip_fp16.h>
#include <cmath>

#define BB 8
#define TT 4
#define HH 16
#define DDIM 128
#define RRDIM 64
#define CCDIM 64
#define RANKC 512
#define DMODEL 2048
#define S0C 4096
#define NQ 64      // H*T queries per batch
#define HD 2048    // H*D
#define NACT 3584  // 1024 (q) + 1024 (q_rope) + 512 (kv_down) + 1024 (k_rope)
#define NSC 65     // 64 cache chunks of 64 + 1 new-token chunk
#define SPAD 4160
#define SCALE_ATT 0.08838834764831845f  // 1/sqrt(128)
#define LP 72      // padded bf16 tile row stride (144 B -> 2-way bank aliasing, free)
#define OLP 136    // o_lds row stride

typedef __attribute__((ext_vector_type(8))) short bf16x8;
typedef __attribute__((ext_vector_type(4))) float f32x4;
typedef unsigned short ushortT;

// padded LDS index for proj A-tile
#define AIDX(row, kk) ((row)*132 + (((row)>>2)<<2) + (kk))

static __device__ __forceinline__ unsigned short f2bf(float x) {
  unsigned u = __float_as_uint(x);
  u += 0x7FFFu + ((u >> 16) & 1u);
  return (unsigned short)(u >> 16);
}
static __device__ __forceinline__ float bf2f(unsigned v16) {
  return __uint_as_float(v16 << 16);
}
static __device__ __forceinline__ unsigned pk2(float a, float b) {
  return (unsigned)f2bf(a) | ((unsigned)f2bf(b) << 16);
}

// ---------------- L0: fused front projections + c_kv bf16 chunk-transpose + pad-zero
// blocks [0,448): proj4; [448,960): transpose cvt; [960,968): zero chunk-64 ckvT
__global__ __launch_bounds__(256) void k_front(const float* __restrict__ A,
                                               const float* __restrict__ w0,
                                               const float* __restrict__ w1,
                                               const float* __restrict__ w2,
                                               const float* __restrict__ w3,
                                               const float* __restrict__ cckv,
                                               float* __restrict__ part,
                                               ushortT* __restrict__ ckvT) {
  __shared__ float shf[4352];
  const int tid = threadIdx.x;
  const int bx = blockIdx.x;
  if (bx < 448) {
    const int cb = bx % 28;
    const int k0 = (bx / 28) * 128;
    const float* W; int N, lc0, off;
    if (cb < 8)       { W = w0; N = 1024; lc0 = cb * 128;        off = 0; }
    else if (cb < 16) { W = w1; N = 1024; lc0 = (cb - 8) * 128;  off = 1024; }
    else if (cb < 20) { W = w2; N = 512;  lc0 = (cb - 16) * 128; off = 2048; }
    else              { W = w3; N = 1024; lc0 = (cb - 20) * 128; off = 2560; }
    {
      const int row = tid >> 3;
      const int kseg = (tid & 7) * 16;
      const float4* s4 = reinterpret_cast<const float4*>(A + (size_t)row * DMODEL + k0 + kseg);
      float4 v0 = s4[0], v1 = s4[1], v2 = s4[2], v3 = s4[3];
      *reinterpret_cast<float4*>(&shf[AIDX(row, kseg)])      = v0;
      *reinterpret_cast<float4*>(&shf[AIDX(row, kseg + 4)])  = v1;
      *reinterpret_cast<float4*>(&shf[AIDX(row, kseg + 8)])  = v2;
      *reinterpret_cast<float4*>(&shf[AIDX(row, kseg + 12)]) = v3;
    }
    __syncthreads();
    const int cg = tid & 31;
    const int rg = tid >> 5;
    float acc[4][4];
    #pragma unroll
    for (int r = 0; r < 4; ++r)
      #pragma unroll
      for (int c = 0; c < 4; ++c) acc[r][c] = 0.f;
    #pragma unroll 4
    for (int kk = 0; kk < 128; ++kk) {
      const float4 w4 = *reinterpret_cast<const float4*>(W + (size_t)(k0 + kk) * N + lc0 + cg * 4);
      const float wv[4] = {w4.x, w4.y, w4.z, w4.w};
      #pragma unroll
      for (int r = 0; r < 4; ++r) {
        const float av = shf[AIDX(rg * 4 + r, kk)];
        #pragma unroll
        for (int c = 0; c < 4; ++c) acc[r][c] = fmaf(av, wv[c], acc[r][c]);
      }
    }
    #pragma unroll
    for (int r = 0; r < 4; ++r) {
      float4 o = make_float4(acc[r][0], acc[r][1], acc[r][2], acc[r][3]);
      *reinterpret_cast<float4*>(part + ((size_t)(bx / 28) * 32 + rg * 4 + r) * NACT + off + lc0 + cg * 4) = o;
    }
  } else if (bx < 960) {
    ushortT* tlds = reinterpret_cast<ushortT*>(shf);   // [64 s][136 r-slab]
    const int idx = bx - 448;
    const int b = idx >> 6, c = idx & 63;
    const float* src = cckv + ((size_t)b * S0C + c * 64) * RANKC;
    ushortT* dstT = ckvT + ((size_t)(b * NSC + c) * RANKC) * 64;
    const int s = tid >> 2, rq = tid & 3;
    const int rloc = tid >> 1, shalf = (tid & 1) * 32;
    for (int slab = 0; slab < 4; ++slab) {
      const int r0 = slab * 128;
      #pragma unroll
      for (int i = 0; i < 8; ++i) {
        const float4 v = *reinterpret_cast<const float4*>(src + (size_t)s * RANKC + r0 + rq * 32 + i * 4);
        *reinterpret_cast<uint2*>(&tlds[s * 136 + rq * 32 + i * 4]) =
            make_uint2(pk2(v.x, v.y), pk2(v.z, v.w));
      }
      __syncthreads();
      alignas(16) ushortT a[32];
      #pragma unroll
      for (int j = 0; j < 32; ++j) a[j] = tlds[(shalf + j) * 136 + rloc];
      uint4* d = reinterpret_cast<uint4*>(dstT + ((size_t)(r0 + rloc)) * 64 + shalf);
      const uint4* ap = reinterpret_cast<const uint4*>(a);
      d[0] = ap[0]; d[1] = ap[1]; d[2] = ap[2]; d[3] = ap[3];
      __syncthreads();
    }
  } else {
    const int b = bx - 960;
    uint4* p = reinterpret_cast<uint4*>(ckvT + ((size_t)(b * NSC + 64) * RANKC) * 64);
    const uint4 z = make_uint4(0, 0, 0, 0);
    for (int i = tid; i < 2048; i += 256) p[i] = z;
  }
}

// ---------------- plain skinny GEMM for the w_out epilogue
__global__ __launch_bounds__(256) void k_proj(const float* __restrict__ A,
                                              const float* __restrict__ W,
                                              float* __restrict__ part,
                                              int N, int NTOT, int coloff) {
  __shared__ float a_lds[4352];
  const int tid = threadIdx.x;
  const int c0 = blockIdx.x * 128;
  const int k0 = blockIdx.y * 128;
  {
    const int row = tid >> 3;
    const int kseg = (tid & 7) * 16;
    const float4* s4 = reinterpret_cast<const float4*>(A + (size_t)row * DMODEL + k0 + kseg);
    float4 v0 = s4[0], v1 = s4[1], v2 = s4[2], v3 = s4[3];
    *reinterpret_cast<float4*>(&a_lds[AIDX(row, kseg)])      = v0;
    *reinterpret_cast<float4*>(&a_lds[AIDX(row, kseg + 4)])  = v1;
    *reinterpret_cast<float4*>(&a_lds[AIDX(row, kseg + 8)])  = v2;
    *reinterpret_cast<float4*>(&a_lds[AIDX(row, kseg + 12)]) = v3;
  }
  __syncthreads();
  const int cg = tid & 31;
  const int rg = tid >> 5;
  float acc[4][4];
  #pragma unroll
  for (int r = 0; r < 4; ++r)
    #pragma unroll
    for (int c = 0; c < 4; ++c) acc[r][c] = 0.f;
  #pragma unroll 4
  for (int kk = 0; kk < 128; ++kk) {
    const float4 w4 = *reinterpret_cast<const float4*>(W + (size_t)(k0 + kk) * N + c0 + cg * 4);
    const float wv[4] = {w4.x, w4.y, w4.z, w4.w};
    #pragma unroll
    for (int r = 0; r < 4; ++r) {
      const float av = a_lds[AIDX(rg * 4 + r, kk)];
      #pragma unroll
      for (int c = 0; c < 4; ++c) acc[r][c] = fmaf(av, wv[c], acc[r][c]);
    }
  }
  #pragma unroll
  for (int r = 0; r < 4; ++r) {
    float4 o = make_float4(acc[r][0], acc[r][1], acc[r][2], acc[r][3]);
    *reinterpret_cast<float4*>(part + ((size_t)blockIdx.y * 32 + rg * 4 + r) * NTOT + coloff + c0 + cg * 4) = o;
  }
}

// ---------------- reduce K-splits
__global__ __launch_bounds__(256) void k_reduce(const float* __restrict__ part,
                                                float* __restrict__ out, int total, int nsplit) {
  int g = blockIdx.x * 256 + threadIdx.x;
  if (g >= total) return;
  float s = 0.f;
  #pragma unroll 4
  for (int c = 0; c < nsplit; ++c) s += part[(size_t)c * total + g];
  out[g] = s;
}

// ---------------- fused q_lat(bf16) + RoPE + c_kv_new (fp32 + bf16 into ckvT chunk 64)
__global__ __launch_bounds__(256) void k_qlatrope(const float* __restrict__ act,
                                                  const float* __restrict__ wup,
                                                  ushortT* __restrict__ qlat,
                                                  float* __restrict__ qrope,
                                                  float* __restrict__ ckvn,
                                                  float* __restrict__ krn,
                                                  ushortT* __restrict__ ckvT) {
  __shared__ float wt[64 * 132];
  __shared__ float a_s[32 * 68];
  const int tid = threadIdx.x;
  const int bx = blockIdx.x;
  if (bx < 64) {
    const int h = bx & 15;
    const int r0 = (bx >> 4) * 128;
    {
      const int r = tid >> 1;
      const int cseg = (tid & 1) * 32;
      const float* src = wup + (size_t)(r0 + r) * HD + h * DDIM + cseg;
      #pragma unroll
      for (int u = 0; u < 8; ++u) {
        const float4 v = *reinterpret_cast<const float4*>(src + u * 4);
        wt[(cseg + u * 4 + 0) * 132 + r] = v.x;
        wt[(cseg + u * 4 + 1) * 132 + r] = v.y;
        wt[(cseg + u * 4 + 2) * 132 + r] = v.z;
        wt[(cseg + u * 4 + 3) * 132 + r] = v.w;
      }
    }
    {
      const int bt = tid >> 3;
      const int cseg = (tid & 7) * 8;
      const float4* s4 = reinterpret_cast<const float4*>(act + (size_t)bt * NACT + h * CCDIM + cseg);
      float4 v0 = s4[0], v1 = s4[1];
      *reinterpret_cast<float4*>(&a_s[bt * 68 + cseg])     = v0;
      *reinterpret_cast<float4*>(&a_s[bt * 68 + cseg + 4]) = v1;
    }
    __syncthreads();
    const int r = tid & 127;
    const int bth = tid >> 7;
    float acc[16];
    #pragma unroll
    for (int i = 0; i < 16; ++i) acc[i] = 0.f;
    #pragma unroll 8
    for (int c = 0; c < 64; ++c) {
      const float wv = wt[c * 132 + r];
      #pragma unroll
      for (int i = 0; i < 16; ++i)
        acc[i] = fmaf(a_s[(bth * 16 + i) * 68 + c], wv, acc[i]);
    }
    #pragma unroll
    for (int i = 0; i < 16; ++i) {
      const int bt = bth * 16 + i;
      const int b = bt >> 2, t = bt & 3;
      qlat[((size_t)(b * NQ) + h * TT + t) * RANKC + r0 + r] = f2bf(acc[i]);
    }
    return;
  }
  int g = (bx - 64) * 256 + tid;
  if (g < BB * TT * HH * 32) {                  // q_rope pairs
    const int hj = g & 31;
    const int h = (g >> 5) & 15;
    const int t = (g >> 9) & 3;
    const int b = g >> 11;
    const float* arow = act + (size_t)(b * TT + t) * NACT + 1024 + h * RRDIM;
    const float x1 = arow[hj], x2 = arow[hj + 32];
    const double fr = (double)(S0C + t) * pow(10000.0, -(double)hj / 32.0);
    const float cs = (float)cos(fr), sn = (float)sin(fr);
    const int qi = h * TT + t;
    qrope[((size_t)b * NQ + qi) * RRDIM + hj]      = x1 * cs - x2 * sn;
    qrope[((size_t)b * NQ + qi) * RRDIM + hj + 32] = x1 * sn + x2 * cs;
    return;
  }
  g -= BB * TT * HH * 32;
  if (g < BB * TT * HH * 32) {                  // k_rope_new pairs -> [b][t][h][R]
    const int hj = g & 31;
    const int h = (g >> 5) & 15;
    const int t = (g >> 9) & 3;
    const int b = g >> 11;
    const float* arow = act + (size_t)(b * TT + t) * NACT + 2560 + h * RRDIM;
    const float x1 = arow[hj], x2 = arow[hj + 32];
    const double fr = (double)(S0C + t) * pow(10000.0, -(double)hj / 32.0);
    const float cs = (float)cos(fr), sn = (float)sin(fr);
    krn[((size_t)(b * TT + t) * HH + h) * RRDIM + hj]      = x1 * cs - x2 * sn;
    krn[((size_t)(b * TT + t) * HH + h) * RRDIM + hj + 32] = x1 * sn + x2 * cs;
    return;
  }
  g -= BB * TT * HH * 32;
  if (g < BB * TT * RANKC) {                    // c_kv_new: fp32 copy + bf16 into ckvT[b][64][r][t]
    const int r = g & 511;
    const int bt = g >> 9;
    const int b = bt >> 2, t = bt & 3;
    const float v = act[(size_t)bt * NACT + 2048 + r];
    ckvn[g] = v;
    ckvT[(((size_t)(b * NSC + 64) * RANKC) + r) * 64 + t] = f2bf(v);
  }
}

// ---------------- rope scores (pre-scaled, fp16): rs[b][h][t][SPAD]
__global__ __launch_bounds__(256) void k_rscore(const float* __restrict__ cache_kr,
                                                const float* __restrict__ krn,
                                                const float* __restrict__ qrope,
                                                __half* __restrict__ rs) {
  const int bh = blockIdx.x;
  const int b = bh >> 4, h = bh & 15;
  const int tid = threadIdx.x;
  const int ql = tid & 3;
  float4 qf[4][4];
  const float* qrb = qrope + ((size_t)b * NQ + h * TT) * RRDIM;
  #pragma unroll
  for (int t = 0; t < 4; ++t)
    #pragma unroll
    for (int u = 0; u < 4; ++u)
      qf[t][u] = *reinterpret_cast<const float4*>(qrb + t * RRDIM + ql * 16 + u * 4);
  const int s0 = blockIdx.y * 512;
  #pragma unroll 1
  for (int pass = 0; pass < 8; ++pass) {
    const int s = s0 + pass * 64 + (tid >> 2);
    if (s < 4100) {
      const float* krow = (s < S0C)
        ? cache_kr + (((size_t)b * S0C + s) * HH + h) * RRDIM
        : krn + (((size_t)b * TT + (s - S0C)) * HH + h) * RRDIM;
      float p[4] = {0.f, 0.f, 0.f, 0.f};
      #pragma unroll
      for (int u = 0; u < 4; ++u) {
        const float4 kv = *reinterpret_cast<const float4*>(krow + ql * 16 + u * 4);
        #pragma unroll
        for (int t = 0; t < 4; ++t) {
          p[t] += kv.x * qf[t][u].x + kv.y * qf[t][u].y
                + kv.z * qf[t][u].z + kv.w * qf[t][u].w;
        }
      }
      #pragma unroll
      for (int t = 0; t < 4; ++t) {
        p[t] += __shfl_xor(p[t], 1, 4);
        p[t] += __shfl_xor(p[t], 2, 4);
      }
      rs[((size_t)bh * 4 + ql) * SPAD + s] = __float2half(p[ql] * SCALE_ATT);
    }
  }
}

// ---------------- phase 1: MFMA latent flash attention partials per (b, chunk)
// grid (8 b, 65 chunks) -> XCD = b. 256 thr = 4 waves; wave w owns q-strip [16w,16w+16).
__global__ __launch_bounds__(256) void k_attn(
    const float* __restrict__ cache_ckv, const float* __restrict__ ckvn,
    const ushortT* __restrict__ qlat, const ushortT* __restrict__ ckvT,
    const __half* __restrict__ rs, float* __restrict__ ml,
    ushortT* __restrict__ olat) {
  __shared__ ushortT smem[23040];      // 46080 B
  ushortT* const QA0 = smem;           // [64 q][72]
  ushortT* const QA1 = smem + 4608;
  ushortT* const KB0 = smem + 9216;    // [64 s][72]
  ushortT* const KB1 = smem + 13824;
  ushortT* const CT  = smem;           // phase C: [128 r][72]
  ushortT* const OL  = smem + 9216;    // phase C: [64 q][136]
  ushortT* const PL  = smem + 18432;   // [64 q][72] bf16 P

  const int tid = threadIdx.x;
  const int lane = tid & 63;
  const int wv = tid >> 6;
  const int m0 = wv * 16;
  const int lm = lane & 15;
  const int lg = lane >> 4;
  const int b = blockIdx.x, chunk = blockIdx.y;
  const int scnt = (chunk < 64) ? 64 : TT;
  const float* bsrc = (chunk < 64)
      ? cache_ckv + ((size_t)b * S0C + (size_t)chunk * 64) * RANKC
      : ckvn + (size_t)b * TT * RANKC;
  const ushortT* qsrc = qlat + (size_t)b * NQ * RANKC;

  // ---- preload rope scores (16 halfs/lane); issued first to hide latency
  float rv[4][4];
  #pragma unroll
  for (int reg = 0; reg < 4; ++reg) {
    const int q = m0 + lg * 4 + reg;
    const __half* rp = rs + ((size_t)(b * HH + (q >> 2)) * TT + (q & 3)) * SPAD + chunk * 64;
    #pragma unroll
    for (int st = 0; st < 4; ++st)
      rv[reg][st] = __half2float(rp[st * 16 + lm]);
  }

  // ---- phase A: S[64q][64s] = qlat . ckv^T via MFMA, K=512 in 8 tiles of 64
  const int srow = tid >> 2;
  const int rseg = (tid & 3) * 16;
  uint4 qreg[2];
  float4 kreg[4];
  auto loadStageA = [&](int kt) {
    const uint4* qp = reinterpret_cast<const uint4*>(qsrc + (size_t)srow * RANKC + kt * 64 + rseg);
    qreg[0] = qp[0]; qreg[1] = qp[1];
    if (srow < scnt) {
      const float4* kp = reinterpret_cast<const float4*>(bsrc + (size_t)srow * RANKC + kt * 64 + rseg);
      kreg[0] = kp[0]; kreg[1] = kp[1]; kreg[2] = kp[2]; kreg[3] = kp[3];
    } else {
      kreg[0] = make_float4(0.f, 0.f, 0.f, 0.f); kreg[1] = kreg[0]; kreg[2] = kreg[0]; kreg[3] = kreg[0];
    }
  };
  auto writeStageA = [&](ushortT* qa, ushortT* kb) {
    *reinterpret_cast<uint4*>(&qa[srow * LP + rseg])     = qreg[0];
    *reinterpret_cast<uint4*>(&qa[srow * LP + rseg + 8]) = qreg[1];
    *reinterpret_cast<uint4*>(&kb[srow * LP + rseg]) =
        make_uint4(pk2(kreg[0].x, kreg[0].y), pk2(kreg[0].z, kreg[0].w),
                   pk2(kreg[1].x, kreg[1].y), pk2(kreg[1].z, kreg[1].w));
    *reinterpret_cast<uint4*>(&kb[srow * LP + rseg + 8]) =
        make_uint4(pk2(kreg[2].x, kreg[2].y), pk2(kreg[2].z, kreg[2].w),
                   pk2(kreg[3].x, kreg[3].y), pk2(kreg[3].z, kreg[3].w));
  };

  f32x4 acc[4];
  #pragma unroll
  for (int st = 0; st < 4; ++st) acc[st] = (f32x4){0.f, 0.f, 0.f, 0.f};

  loadStageA(0);
  writeStageA(QA0, KB0);
  loadStageA(1);
  __syncthreads();
  for (int kt = 0; kt < 8; ++kt) {
    if (kt < 7) {
      writeStageA((kt & 1) ? QA0 : QA1, (kt & 1) ? KB0 : KB1);
      if (kt < 6) loadStageA(kt + 2);
    }
    const ushortT* qa = (kt & 1) ? QA1 : QA0;
    const ushortT* kb = (kt & 1) ? KB1 : KB0;
    #pragma unroll
    for (int ks = 0; ks < 2; ++ks) {
      const bf16x8 af = *reinterpret_cast<const bf16x8*>(&qa[(m0 + lm) * LP + ks * 32 + lg * 8]);
      #pragma unroll
      for (int st = 0; st < 4; ++st) {
        const bf16x8 bfv = *reinterpret_cast<const bf16x8*>(&kb[(st * 16 + lm) * LP + ks * 32 + lg * 8]);
        acc[st] = __builtin_amdgcn_mfma_f32_16x16x32_bf16(af, bfv, acc[st], 0, 0, 0);
      }
    }
    __syncthreads();
  }

  // ---- issue phase-C rg0 global loads early (hide under softmax)
  const ushortT* ctsrc = ckvT + ((size_t)(b * NSC + chunk) * RANKC) * 64;
  const int rloc = tid >> 1;
  const int shalf = (tid & 1) * 32;
  uint4 creg[4];
  auto loadCT = [&](int rg) {
    const uint4* p = reinterpret_cast<const uint4*>(ctsrc + ((size_t)(rg * 128 + rloc)) * 64 + shalf);
    creg[0] = p[0]; creg[1] = p[1]; creg[2] = p[2]; creg[3] = p[3];
  };
  auto writeCT = [&]() {
    uint4* d = reinterpret_cast<uint4*>(&CT[rloc * LP + shalf]);
    d[0] = creg[0]; d[1] = creg[1]; d[2] = creg[2]; d[3] = creg[3];
  };
  loadCT(0);

  // ---- partial softmax; D-frag: s = st*16+lm, q = m0 + lg*4 + reg
  #pragma unroll
  for (int reg = 0; reg < 4; ++reg) {
    const int q = m0 + lg * 4 + reg;
    float vv[4];
    float mx = -1e30f;
    #pragma unroll
    for (int st = 0; st < 4; ++st) {
      const int sl = st * 16 + lm;
      const float val = (sl < scnt) ? fmaf(acc[st][reg], SCALE_ATT, rv[reg][st]) : -1e30f;
      vv[st] = val;
      mx = fmaxf(mx, val);
    }
    #pragma unroll
    for (int off = 1; off < 16; off <<= 1) mx = fmaxf(mx, __shfl_xor(mx, off, 16));
    float sum = 0.f;
    #pragma unroll
    for (int st = 0; st < 4; ++st) {
      const float p = __expf(vv[st] - mx);
      vv[st] = p;
      sum += p;
    }
    #pragma unroll
    for (int off = 1; off < 16; off <<= 1) sum += __shfl_xor(sum, off, 16);
    #pragma unroll
    for (int st = 0; st < 4; ++st)
      PL[q * LP + st * 16 + lm] = f2bf(vv[st]);
    if (lm == 0) {
      const size_t mb = (((size_t)b * NSC + chunk) * NQ + q) * 2;
      ml[mb] = mx; ml[mb + 1] = sum;
    }
  }
  __syncthreads();   // phase-A reads done everywhere; PL visible; CT region free

  writeCT();
  loadCT(1);
  const bf16x8 pa0 = *reinterpret_cast<const bf16x8*>(&PL[(m0 + lm) * LP + lg * 8]);
  const bf16x8 pa1 = *reinterpret_cast<const bf16x8*>(&PL[(m0 + lm) * LP + 32 + lg * 8]);
  __syncthreads();   // CT rg0 visible

  // ---- phase C: O[64q][512r] = P . ckv via MFMA, 4 r-groups of 128
  const size_t obase = ((size_t)(b * NSC + chunk) * NQ) * RANKC;  // ushort idx
  for (int rg = 0; rg < 4; ++rg) {
    f32x4 a2[8];
    #pragma unroll
    for (int nt = 0; nt < 8; ++nt) a2[nt] = (f32x4){0.f, 0.f, 0.f, 0.f};
    #pragma unroll
    for (int nt = 0; nt < 8; ++nt) {
      const bf16x8 b0 = *reinterpret_cast<const bf16x8*>(&CT[(nt * 16 + lm) * LP + lg * 8]);
      const bf16x8 b1 = *reinterpret_cast<const bf16x8*>(&CT[(nt * 16 + lm) * LP + 32 + lg * 8]);
      a2[nt] = __builtin_amdgcn_mfma_f32_16x16x32_bf16(pa0, b0, a2[nt], 0, 0, 0);
      a2[nt] = __builtin_amdgcn_mfma_f32_16x16x32_bf16(pa1, b1, a2[nt], 0, 0, 0);
    }
    #pragma unroll
    for (int nt = 0; nt < 8; ++nt)
      #pragma unroll
      for (int reg = 0; reg < 4; ++reg)
        OL[(m0 + lg * 4 + reg) * OLP + nt * 16 + lm] = f2bf(a2[nt][reg]);
    __syncthreads();   // CT reads + OL writes complete
    {
      const int q = tid >> 2;
      const int seg = (tid & 3) * 32;
      const uint4* s4 = reinterpret_cast<const uint4*>(&OL[q * OLP + seg]);
      uint4* d4 = reinterpret_cast<uint4*>(&olat[obase + (size_t)q * RANKC + rg * 128 + seg]);
      d4[0] = s4[0]; d4[1] = s4[1]; d4[2] = s4[2]; d4[3] = s4[3];
    }
    if (rg < 3) {
      writeCT();
      if (rg < 2) loadCT(rg + 2);
      __syncthreads();  // next CT visible; OL free to rewrite
    }
  }
}

// ---------------- fused combine + out_head epilogue (olat bf16)
__global__ __launch_bounds__(512) void k_combF(const float* __restrict__ ml,
                                               const ushortT* __restrict__ olat,
                                               const float* __restrict__ wup,
                                               float* __restrict__ ohead) {
  __shared__ float wrow[4][66];
  __shared__ float att_lds[4][516];
  const int h = blockIdx.x, b = blockIdx.y;
  const int tid = threadIdx.x;
  const int wave = tid >> 6;
  const int i = wave >> 1;
  const int rhalf = wave & 1;
  const int rl = tid & 63;
  const int qi = h * TT + i;
  float m1 = -1e30f, l1 = 0.f, m2 = -1e30f, l2 = 0.f;
  {
    const size_t base = (((size_t)b * NSC + rl) * NQ + qi) * 2;
    m1 = ml[base]; l1 = ml[base + 1];
    if (rl == 0) {
      const size_t b2 = (((size_t)b * NSC + 64) * NQ + qi) * 2;
      m2 = ml[b2]; l2 = ml[b2 + 1];
    }
  }
  float M = fmaxf(m1, m2);
  #pragma unroll
  for (int off = 1; off < 64; off <<= 1) M = fmaxf(M, __shfl_xor(M, off));
  float L = l1 * __expf(m1 - M) + ((rl == 0) ? l2 * __expf(m2 - M) : 0.f);
  #pragma unroll
  for (int off = 1; off < 64; off <<= 1) L += __shfl_xor(L, off);
  const float invL = 1.0f / L;
  wrow[i][rl] = __expf(m1 - M) * invL;
  if (rl == 0) wrow[i][64] = __expf(m2 - M) * invL;
  __syncthreads();
  const int r0 = rhalf * 256 + rl * 4;
  float o0 = 0.f, o1 = 0.f, o2 = 0.f, o3 = 0.f;
  for (int c = 0; c < NSC; ++c) {
    const float w = wrow[i][c];
    const uint2 v = *reinterpret_cast<const uint2*>(
        olat + (((size_t)b * NSC + c) * NQ + qi) * RANKC + r0);
    o0 = fmaf(bf2f(v.x & 0xffffu), w, o0);
    o1 = fmaf(bf2f(v.x >> 16), w, o1);
    o2 = fmaf(bf2f(v.y & 0xffffu), w, o2);
    o3 = fmaf(bf2f(v.y >> 16), w, o3);
  }
  *reinterpret_cast<float4*>(&att_lds[i][r0]) = make_float4(o0, o1, o2, o3);
  __syncthreads();
  const int col = tid & 127;
  const int t = tid >> 7;
  float acc = 0.f;
  #pragma unroll 8
  for (int r = 0; r < RANKC; ++r)
    acc = fmaf(att_lds[t][r], wup[(size_t)r * HD + h * DDIM + col], acc);
  ohead[(size_t)(b * TT + t) * HD + h * DDIM + col] = acc;
}

extern "C" void kernel_launch(void* const* d_in, const int* in_sizes, int n_in,
                              void* d_out, int out_size, void* d_ws, size_t ws_size,
                              hipStream_t stream) {
  const float* x     = (const float*)d_in[0];
  const float* cckv  = (const float*)d_in[1];
  const float* ckr   = (const float*)d_in[2];
  const float* w_q   = (const float*)d_in[3];
  const float* w_qr  = (const float*)d_in[4];
  const float* w_kvd = (const float*)d_in[5];
  const float* w_kvu = (const float*)d_in[6];
  const float* w_kr  = (const float*)d_in[7];
  const float* w_out = (const float*)d_in[8];
  float* out = (float*)d_out;
  float* ws = (float*)d_ws;

  size_t off = 0;
  float* act      = ws + off; off += 32ull * NACT;                  // 114688
  ushortT* qlat   = (ushortT*)(ws + off); off += 131072;            // 8*64*512 bf16
  float* qrope    = ws + off; off += 32768;
  float* ckvn     = ws + off; off += 16384;
  float* krn      = ws + off; off += 32768;
  float* mlb      = ws + off; off += (size_t)BB * NSC * NQ * 2;     // 66560
  float* ohead    = ws + off; off += 65536;
  __half* rsb     = (__half*)(ws + off); off += 1064960;            // 512*4160 fp16
  ushortT* ckvT   = (ushortT*)(ws + off); off += 8519680;           // 8*65*512*64 bf16
  // region B (time-shared): part0 -> olat(bf16) -> part3
  float* regB  = ws + off;
  float* part0 = regB;
  ushortT* olat = (ushortT*)regB;                                   // 8*65*64*512 bf16
  float* part3 = regB;

  k_front<<<dim3(968), 256, 0, stream>>>(x, w_q, w_qr, w_kvd, w_kr, cckv, part0, ckvT);
  k_reduce<<<dim3(448), 256, 0, stream>>>(part0, act, 32 * NACT, 16);
  k_qlatrope<<<dim3(256), 256, 0, stream>>>(act, w_kvu, qlat, qrope, ckvn, krn, ckvT);
  k_rscore<<<dim3(128, 9), 256, 0, stream>>>(ckr, krn, qrope, rsb);

  k_attn<<<dim3(BB, NSC), 256, 0, stream>>>(cckv, ckvn, qlat, ckvT, rsb, mlb, olat);

  k_combF<<<dim3(16, 8), 512, 0, stream>>>(mlb, olat, w_kvu, ohead);
  k_proj<<<dim3(16, 16), 256, 0, stream>>>(ohead, w_out, part3, 2048, 2048, 0);
  k_reduce<<<dim3(256), 256, 0, stream>>>(part3, out, 32 * HD, 16);
}

// Round 6
// 235.779 us; speedup vs baseline: 1.0247x; 1.0247x over previous
//
#include <hip/hip_runtime.h>
#include <hip/hip_fp16.h>
#include <cmath>

#define BB 8
#define TT 4
#define HH 16
#define DDIM 128
#define RRDIM 64
#define CCDIM 64
#define RANKC 512
#define DMODEL 2048
#define S0C 4096
#define NQ 64      // H*T queries per batch
#define HD 2048    // H*D
#define NACT 3584
#define NSC 65     // 64 cache chunks of 64 + 1 new-token chunk
#define NG 17      // 16 groups of 4 chunks + 1 new-token group
#define SPAD 4160
#define SCALE_ATT 0.08838834764831845f  // 1/sqrt(128)
#define LP 72      // padded bf16 tile row stride

typedef __attribute__((ext_vector_type(8))) short bf16x8;
typedef __attribute__((ext_vector_type(4))) float f32x4;
typedef unsigned short ushortT;

#define AIDX(row, kk) ((row)*132 + (((row)>>2)<<2) + (kk))

static __device__ __forceinline__ unsigned short f2bf(float x) {
  unsigned u = __float_as_uint(x);
  u += 0x7FFFu + ((u >> 16) & 1u);
  return (unsigned short)(u >> 16);
}
static __device__ __forceinline__ float bf2f(unsigned v16) {
  return __uint_as_float(v16 << 16);
}
static __device__ __forceinline__ unsigned pk2(float a, float b) {
  return (unsigned)f2bf(a) | ((unsigned)f2bf(b) << 16);
}

// ---------------- L0: fused front projections + c_kv bf16 chunk-transpose + pad-zero
__global__ __launch_bounds__(256) void k_front(const float* __restrict__ A,
                                               const float* __restrict__ w0,
                                               const float* __restrict__ w1,
                                               const float* __restrict__ w2,
                                               const float* __restrict__ w3,
                                               const float* __restrict__ cckv,
                                               float* __restrict__ part,
                                               ushortT* __restrict__ ckvT) {
  __shared__ float shf[4352];
  const int tid = threadIdx.x;
  const int bx = blockIdx.x;
  if (bx < 448) {
    const int cb = bx % 28;
    const int k0 = (bx / 28) * 128;
    const float* W; int N, lc0, off;
    if (cb < 8)       { W = w0; N = 1024; lc0 = cb * 128;        off = 0; }
    else if (cb < 16) { W = w1; N = 1024; lc0 = (cb - 8) * 128;  off = 1024; }
    else if (cb < 20) { W = w2; N = 512;  lc0 = (cb - 16) * 128; off = 2048; }
    else              { W = w3; N = 1024; lc0 = (cb - 20) * 128; off = 2560; }
    {
      const int row = tid >> 3;
      const int kseg = (tid & 7) * 16;
      const float4* s4 = reinterpret_cast<const float4*>(A + (size_t)row * DMODEL + k0 + kseg);
      float4 v0 = s4[0], v1 = s4[1], v2 = s4[2], v3 = s4[3];
      *reinterpret_cast<float4*>(&shf[AIDX(row, kseg)])      = v0;
      *reinterpret_cast<float4*>(&shf[AIDX(row, kseg + 4)])  = v1;
      *reinterpret_cast<float4*>(&shf[AIDX(row, kseg + 8)])  = v2;
      *reinterpret_cast<float4*>(&shf[AIDX(row, kseg + 12)]) = v3;
    }
    __syncthreads();
    const int cg = tid & 31;
    const int rg = tid >> 5;
    float acc[4][4];
    #pragma unroll
    for (int r = 0; r < 4; ++r)
      #pragma unroll
      for (int c = 0; c < 4; ++c) acc[r][c] = 0.f;
    #pragma unroll 4
    for (int kk = 0; kk < 128; ++kk) {
      const float4 w4 = *reinterpret_cast<const float4*>(W + (size_t)(k0 + kk) * N + lc0 + cg * 4);
      const float wv[4] = {w4.x, w4.y, w4.z, w4.w};
      #pragma unroll
      for (int r = 0; r < 4; ++r) {
        const float av = shf[AIDX(rg * 4 + r, kk)];
        #pragma unroll
        for (int c = 0; c < 4; ++c) acc[r][c] = fmaf(av, wv[c], acc[r][c]);
      }
    }
    #pragma unroll
    for (int r = 0; r < 4; ++r) {
      float4 o = make_float4(acc[r][0], acc[r][1], acc[r][2], acc[r][3]);
      *reinterpret_cast<float4*>(part + ((size_t)(bx / 28) * 32 + rg * 4 + r) * NACT + off + lc0 + cg * 4) = o;
    }
  } else if (bx < 960) {
    ushortT* tlds = reinterpret_cast<ushortT*>(shf);   // [64 s][136]
    const int idx = bx - 448;
    const int b = idx >> 6, c = idx & 63;
    const float* src = cckv + ((size_t)b * S0C + c * 64) * RANKC;
    ushortT* dstT = ckvT + ((size_t)(b * NSC + c) * RANKC) * 64;
    const int s = tid >> 2, rq = tid & 3;
    const int rloc = tid >> 1, shalf = (tid & 1) * 32;
    for (int slab = 0; slab < 4; ++slab) {
      const int r0 = slab * 128;
      #pragma unroll
      for (int i = 0; i < 8; ++i) {
        const float4 v = *reinterpret_cast<const float4*>(src + (size_t)s * RANKC + r0 + rq * 32 + i * 4);
        *reinterpret_cast<uint2*>(&tlds[s * 136 + rq * 32 + i * 4]) =
            make_uint2(pk2(v.x, v.y), pk2(v.z, v.w));
      }
      __syncthreads();
      // pack 32 ushorts (rows shalf..shalf+31 of col rloc) into 16 uints, fully static
      unsigned wv[16];
      #pragma unroll
      for (int k = 0; k < 16; ++k) {
        const unsigned t0 = tlds[(shalf + 2 * k)     * 136 + rloc];
        const unsigned t1 = tlds[(shalf + 2 * k + 1) * 136 + rloc];
        wv[k] = t0 | (t1 << 16);
      }
      uint4* d = reinterpret_cast<uint4*>(dstT + ((size_t)(r0 + rloc)) * 64 + shalf);
      d[0] = make_uint4(wv[0], wv[1], wv[2], wv[3]);
      d[1] = make_uint4(wv[4], wv[5], wv[6], wv[7]);
      d[2] = make_uint4(wv[8], wv[9], wv[10], wv[11]);
      d[3] = make_uint4(wv[12], wv[13], wv[14], wv[15]);
      __syncthreads();
    }
  } else {
    const int b = bx - 960;
    uint4* p = reinterpret_cast<uint4*>(ckvT + ((size_t)(b * NSC + 64) * RANKC) * 64);
    const uint4 z = make_uint4(0, 0, 0, 0);
    for (int i = tid; i < 4096; i += 256) p[i] = z;
  }
}

// ---------------- plain skinny GEMM for the w_out epilogue
__global__ __launch_bounds__(256) void k_proj(const float* __restrict__ A,
                                              const float* __restrict__ W,
                                              float* __restrict__ part,
                                              int N, int NTOT, int coloff) {
  __shared__ float a_lds[4352];
  const int tid = threadIdx.x;
  const int c0 = blockIdx.x * 128;
  const int k0 = blockIdx.y * 128;
  {
    const int row = tid >> 3;
    const int kseg = (tid & 7) * 16;
    const float4* s4 = reinterpret_cast<const float4*>(A + (size_t)row * DMODEL + k0 + kseg);
    float4 v0 = s4[0], v1 = s4[1], v2 = s4[2], v3 = s4[3];
    *reinterpret_cast<float4*>(&a_lds[AIDX(row, kseg)])      = v0;
    *reinterpret_cast<float4*>(&a_lds[AIDX(row, kseg + 4)])  = v1;
    *reinterpret_cast<float4*>(&a_lds[AIDX(row, kseg + 8)])  = v2;
    *reinterpret_cast<float4*>(&a_lds[AIDX(row, kseg + 12)]) = v3;
  }
  __syncthreads();
  const int cg = tid & 31;
  const int rg = tid >> 5;
  float acc[4][4];
  #pragma unroll
  for (int r = 0; r < 4; ++r)
    #pragma unroll
    for (int c = 0; c < 4; ++c) acc[r][c] = 0.f;
  #pragma unroll 4
  for (int kk = 0; kk < 128; ++kk) {
    const float4 w4 = *reinterpret_cast<const float4*>(W + (size_t)(k0 + kk) * N + c0 + cg * 4);
    const float wv[4] = {w4.x, w4.y, w4.z, w4.w};
    #pragma unroll
    for (int r = 0; r < 4; ++r) {
      const float av = a_lds[AIDX(rg * 4 + r, kk)];
      #pragma unroll
      for (int c = 0; c < 4; ++c) acc[r][c] = fmaf(av, wv[c], acc[r][c]);
    }
  }
  #pragma unroll
  for (int r = 0; r < 4; ++r) {
    float4 o = make_float4(acc[r][0], acc[r][1], acc[r][2], acc[r][3]);
    *reinterpret_cast<float4*>(part + ((size_t)blockIdx.y * 32 + rg * 4 + r) * NTOT + coloff + c0 + cg * 4) = o;
  }
}

// ---------------- reduce K-splits
__global__ __launch_bounds__(256) void k_reduce(const float* __restrict__ part,
                                                float* __restrict__ out, int total, int nsplit) {
  int g = blockIdx.x * 256 + threadIdx.x;
  if (g >= total) return;
  float s = 0.f;
  #pragma unroll 4
  for (int c = 0; c < nsplit; ++c) s += part[(size_t)c * total + g];
  out[g] = s;
}

// ---------------- fused q_lat(bf16) + RoPE + c_kv_new
__global__ __launch_bounds__(256) void k_qlatrope(const float* __restrict__ act,
                                                  const float* __restrict__ wup,
                                                  ushortT* __restrict__ qlat,
                                                  float* __restrict__ qrope,
                                                  float* __restrict__ ckvn,
                                                  float* __restrict__ krn,
                                                  ushortT* __restrict__ ckvT) {
  __shared__ float wt[64 * 132];
  __shared__ float a_s[32 * 68];
  const int tid = threadIdx.x;
  const int bx = blockIdx.x;
  if (bx < 64) {
    const int h = bx & 15;
    const int r0 = (bx >> 4) * 128;
    {
      const int r = tid >> 1;
      const int cseg = (tid & 1) * 32;
      const float* src = wup + (size_t)(r0 + r) * HD + h * DDIM + cseg;
      #pragma unroll
      for (int u = 0; u < 8; ++u) {
        const float4 v = *reinterpret_cast<const float4*>(src + u * 4);
        wt[(cseg + u * 4 + 0) * 132 + r] = v.x;
        wt[(cseg + u * 4 + 1) * 132 + r] = v.y;
        wt[(cseg + u * 4 + 2) * 132 + r] = v.z;
        wt[(cseg + u * 4 + 3) * 132 + r] = v.w;
      }
    }
    {
      const int bt = tid >> 3;
      const int cseg = (tid & 7) * 8;
      const float4* s4 = reinterpret_cast<const float4*>(act + (size_t)bt * NACT + h * CCDIM + cseg);
      float4 v0 = s4[0], v1 = s4[1];
      *reinterpret_cast<float4*>(&a_s[bt * 68 + cseg])     = v0;
      *reinterpret_cast<float4*>(&a_s[bt * 68 + cseg + 4]) = v1;
    }
    __syncthreads();
    const int r = tid & 127;
    const int bth = tid >> 7;
    float acc[16];
    #pragma unroll
    for (int i = 0; i < 16; ++i) acc[i] = 0.f;
    #pragma unroll 8
    for (int c = 0; c < 64; ++c) {
      const float wv = wt[c * 132 + r];
      #pragma unroll
      for (int i = 0; i < 16; ++i)
        acc[i] = fmaf(a_s[(bth * 16 + i) * 68 + c], wv, acc[i]);
    }
    #pragma unroll
    for (int i = 0; i < 16; ++i) {
      const int bt = bth * 16 + i;
      const int b = bt >> 2, t = bt & 3;
      qlat[((size_t)(b * NQ) + h * TT + t) * RANKC + r0 + r] = f2bf(acc[i]);
    }
    return;
  }
  int g = (bx - 64) * 256 + tid;
  if (g < BB * TT * HH * 32) {                  // q_rope pairs
    const int hj = g & 31;
    const int h = (g >> 5) & 15;
    const int t = (g >> 9) & 3;
    const int b = g >> 11;
    const float* arow = act + (size_t)(b * TT + t) * NACT + 1024 + h * RRDIM;
    const float x1 = arow[hj], x2 = arow[hj + 32];
    const double fr = (double)(S0C + t) * pow(10000.0, -(double)hj / 32.0);
    const float cs = (float)cos(fr), sn = (float)sin(fr);
    const int qi = h * TT + t;
    qrope[((size_t)b * NQ + qi) * RRDIM + hj]      = x1 * cs - x2 * sn;
    qrope[((size_t)b * NQ + qi) * RRDIM + hj + 32] = x1 * sn + x2 * cs;
    return;
  }
  g -= BB * TT * HH * 32;
  if (g < BB * TT * HH * 32) {                  // k_rope_new pairs
    const int hj = g & 31;
    const int h = (g >> 5) & 15;
    const int t = (g >> 9) & 3;
    const int b = g >> 11;
    const float* arow = act + (size_t)(b * TT + t) * NACT + 2560 + h * RRDIM;
    const float x1 = arow[hj], x2 = arow[hj + 32];
    const double fr = (double)(S0C + t) * pow(10000.0, -(double)hj / 32.0);
    const float cs = (float)cos(fr), sn = (float)sin(fr);
    krn[((size_t)(b * TT + t) * HH + h) * RRDIM + hj]      = x1 * cs - x2 * sn;
    krn[((size_t)(b * TT + t) * HH + h) * RRDIM + hj + 32] = x1 * sn + x2 * cs;
    return;
  }
  g -= BB * TT * HH * 32;
  if (g < BB * TT * RANKC) {                    // c_kv_new: fp32 copy + bf16 into ckvT chunk 64
    const int r = g & 511;
    const int bt = g >> 9;
    const int b = bt >> 2, t = bt & 3;
    const float v = act[(size_t)bt * NACT + 2048 + r];
    ckvn[g] = v;
    ckvT[(((size_t)(b * NSC + 64) * RANKC) + r) * 64 + t] = f2bf(v);
  }
}

// ---------------- rope scores (pre-scaled, fp16)
__global__ __launch_bounds__(256) void k_rscore(const float* __restrict__ cache_kr,
                                                const float* __restrict__ krn,
                                                const float* __restrict__ qrope,
                                                __half* __restrict__ rs) {
  const int bh = blockIdx.x;
  const int b = bh >> 4, h = bh & 15;
  const int tid = threadIdx.x;
  const int ql = tid & 3;
  float4 qf[4][4];
  const float* qrb = qrope + ((size_t)b * NQ + h * TT) * RRDIM;
  #pragma unroll
  for (int t = 0; t < 4; ++t)
    #pragma unroll
    for (int u = 0; u < 4; ++u)
      qf[t][u] = *reinterpret_cast<const float4*>(qrb + t * RRDIM + ql * 16 + u * 4);
  const int s0 = blockIdx.y * 512;
  #pragma unroll 1
  for (int pass = 0; pass < 8; ++pass) {
    const int s = s0 + pass * 64 + (tid >> 2);
    if (s < 4100) {
      const float* krow = (s < S0C)
        ? cache_kr + (((size_t)b * S0C + s) * HH + h) * RRDIM
        : krn + (((size_t)b * TT + (s - S0C)) * HH + h) * RRDIM;
      float p[4] = {0.f, 0.f, 0.f, 0.f};
      #pragma unroll
      for (int u = 0; u < 4; ++u) {
        const float4 kv = *reinterpret_cast<const float4*>(krow + ql * 16 + u * 4);
        #pragma unroll
        for (int t = 0; t < 4; ++t) {
          p[t] += kv.x * qf[t][u].x + kv.y * qf[t][u].y
                + kv.z * qf[t][u].z + kv.w * qf[t][u].w;
        }
      }
      #pragma unroll
      for (int t = 0; t < 4; ++t) {
        p[t] += __shfl_xor(p[t], 1, 4);
        p[t] += __shfl_xor(p[t], 2, 4);
      }
      rs[((size_t)bh * 4 + ql) * SPAD + s] = __float2half(p[ql] * SCALE_ATT);
    }
  }
}

// ---------------- k_score: S = qlat.ckv^T (MFMA) + rope + softmax -> P~ (bf16) + (m,l)
// grid (8 b, 65 chunks), 256 thr = 4 waves
__global__ __launch_bounds__(256) void k_score(
    const float* __restrict__ cckv, const float* __restrict__ ckvn,
    const ushortT* __restrict__ qlat, const __half* __restrict__ rs,
    float* __restrict__ ml, ushortT* __restrict__ Pg) {
  __shared__ ushortT smem[23040];   // 46,080 B -> 3 blocks/CU
  ushortT* const QA0 = smem;
  ushortT* const QA1 = smem + 4608;
  ushortT* const KB0 = smem + 9216;
  ushortT* const KB1 = smem + 13824;
  ushortT* const PL  = smem + 18432;
  const int tid = threadIdx.x;
  const int lane = tid & 63;
  const int wv = tid >> 6;
  const int m0 = wv * 16;
  const int lm = lane & 15;
  const int lg = lane >> 4;
  const int b = blockIdx.x, chunk = blockIdx.y;
  const int scnt = (chunk < 64) ? 64 : TT;
  const float* bsrc = (chunk < 64)
      ? cckv + ((size_t)b * S0C + (size_t)chunk * 64) * RANKC
      : ckvn + (size_t)b * TT * RANKC;
  const ushortT* qsrc = qlat + (size_t)b * NQ * RANKC;

  const int srow = tid >> 2;
  const int rseg = (tid & 3) * 16;
  uint4 qreg[2];
  float4 kreg[4];
  auto loadA = [&](int kt) {
    const uint4* qp = reinterpret_cast<const uint4*>(qsrc + (size_t)srow * RANKC + kt * 64 + rseg);
    qreg[0] = qp[0]; qreg[1] = qp[1];
    if (srow < scnt) {
      const float4* kp = reinterpret_cast<const float4*>(bsrc + (size_t)srow * RANKC + kt * 64 + rseg);
      kreg[0] = kp[0]; kreg[1] = kp[1]; kreg[2] = kp[2]; kreg[3] = kp[3];
    } else {
      kreg[0] = make_float4(0.f, 0.f, 0.f, 0.f); kreg[1] = kreg[0]; kreg[2] = kreg[0]; kreg[3] = kreg[0];
    }
  };
  auto writeA = [&](ushortT* qa, ushortT* kb) {
    *reinterpret_cast<uint4*>(&qa[srow * LP + rseg])     = qreg[0];
    *reinterpret_cast<uint4*>(&qa[srow * LP + rseg + 8]) = qreg[1];
    *reinterpret_cast<uint4*>(&kb[srow * LP + rseg]) =
        make_uint4(pk2(kreg[0].x, kreg[0].y), pk2(kreg[0].z, kreg[0].w),
                   pk2(kreg[1].x, kreg[1].y), pk2(kreg[1].z, kreg[1].w));
    *reinterpret_cast<uint4*>(&kb[srow * LP + rseg + 8]) =
        make_uint4(pk2(kreg[2].x, kreg[2].y), pk2(kreg[2].z, kreg[2].w),
                   pk2(kreg[3].x, kreg[3].y), pk2(kreg[3].z, kreg[3].w));
  };

  f32x4 acc[4];
  #pragma unroll
  for (int st = 0; st < 4; ++st) acc[st] = (f32x4){0.f, 0.f, 0.f, 0.f};

  loadA(0);
  writeA(QA0, KB0);
  loadA(1);
  __syncthreads();
  for (int kt = 0; kt < 8; ++kt) {
    if (kt < 7) {
      writeA((kt & 1) ? QA0 : QA1, (kt & 1) ? KB0 : KB1);
      if (kt < 6) loadA(kt + 2);
    }
    const ushortT* qa = (kt & 1) ? QA1 : QA0;
    const ushortT* kb = (kt & 1) ? KB1 : KB0;
    #pragma unroll
    for (int ks = 0; ks < 2; ++ks) {
      const bf16x8 af = *reinterpret_cast<const bf16x8*>(&qa[(m0 + lm) * LP + ks * 32 + lg * 8]);
      #pragma unroll
      for (int st = 0; st < 4; ++st) {
        const bf16x8 bfv = *reinterpret_cast<const bf16x8*>(&kb[(st * 16 + lm) * LP + ks * 32 + lg * 8]);
        acc[st] = __builtin_amdgcn_mfma_f32_16x16x32_bf16(af, bfv, acc[st], 0, 0, 0);
      }
    }
    __syncthreads();
  }

  // softmax (rope scores read here, L2/L3-hot)
  #pragma unroll
  for (int reg = 0; reg < 4; ++reg) {
    const int q = m0 + lg * 4 + reg;
    const __half* rp = rs + ((size_t)(b * HH + (q >> 2)) * TT + (q & 3)) * SPAD + chunk * 64;
    float vv[4];
    float mx = -1e30f;
    #pragma unroll
    for (int st = 0; st < 4; ++st) {
      const int sl = st * 16 + lm;
      const float val = (sl < scnt)
          ? fmaf(acc[st][reg], SCALE_ATT, __half2float(rp[st * 16 + lm]))
          : -1e30f;
      vv[st] = val;
      mx = fmaxf(mx, val);
    }
    #pragma unroll
    for (int off = 1; off < 16; off <<= 1) mx = fmaxf(mx, __shfl_xor(mx, off, 16));
    float sum = 0.f;
    #pragma unroll
    for (int st = 0; st < 4; ++st) {
      const float p = __expf(vv[st] - mx);
      vv[st] = p;
      sum += p;
    }
    #pragma unroll
    for (int off = 1; off < 16; off <<= 1) sum += __shfl_xor(sum, off, 16);
    #pragma unroll
    for (int st = 0; st < 4; ++st)
      PL[q * LP + st * 16 + lm] = f2bf(vv[st]);
    if (lm == 0) {
      const size_t mb = (((size_t)b * NSC + chunk) * NQ + q) * 2;
      ml[mb] = mx; ml[mb + 1] = sum;
    }
  }
  __syncthreads();

  // P~ store: 128 B per q-row
  {
    const int prow = tid >> 2;
    const int pseg = (tid & 3) * 16;
    const uint4* sp = reinterpret_cast<const uint4*>(&PL[prow * LP + pseg]);
    uint4* dp = reinterpret_cast<uint4*>(Pg + ((size_t)(b * NSC + chunk) * NQ + prow) * 64 + pseg);
    dp[0] = sp[0]; dp[1] = sp[1];
  }
}

// ---------------- k_pv: group-accumulated O partials = sum_c w_c * (P~_c . ckvT_c)
// grid (8 b, 17 g, 4 rg), 256 thr = 4 waves
__global__ __launch_bounds__(256) void k_pv(
    const ushortT* __restrict__ ckvT, const ushortT* __restrict__ Pg,
    const float* __restrict__ ml, float* __restrict__ olat,
    float* __restrict__ mlg) {
  __shared__ ushortT CT[128 * LP];    // 18,432 B
  __shared__ ushortT PLs[64 * LP];    // 9,216 B
  __shared__ float wlds[4][68];
  const int tid = threadIdx.x;
  const int lane = tid & 63;
  const int wv = tid >> 6;
  const int m0 = wv * 16;
  const int lm = lane & 15;
  const int lg = lane >> 4;
  const int b = blockIdx.x, g = blockIdx.y, rg = blockIdx.z;
  const int nc = (g < 16) ? 4 : 1;
  const int c0 = (g < 16) ? g * 4 : 64;

  // pass 1: per-q group max + weights (lm==0 lanes only; q = m0+lg*4+reg)
  if (lm == 0) {
    #pragma unroll
    for (int reg = 0; reg < 4; ++reg) {
      const int q = m0 + lg * 4 + reg;
      float mg = -1e30f;
      for (int c = 0; c < nc; ++c)
        mg = fmaxf(mg, ml[(((size_t)b * NSC + c0 + c) * NQ + q) * 2]);
      float la = 0.f;
      for (int c = 0; c < nc; ++c) {
        const size_t mb = (((size_t)b * NSC + c0 + c) * NQ + q) * 2;
        const float w = __expf(ml[mb] - mg);
        la = fmaf(ml[mb + 1], w, la);
        wlds[c][q] = w;
      }
      if (blockIdx.z == 0) {
        const size_t gb = (((size_t)b * NG + g) * NQ + q) * 2;
        mlg[gb] = mg; mlg[gb + 1] = la;
      }
    }
  }

  const int rloc = tid >> 1;
  const int shalf = (tid & 1) * 32;
  const int prow = tid >> 2;
  const int pseg = (tid & 3) * 16;
  uint4 ctreg[4];
  uint4 plreg[2];
  auto loadc = [&](int c) {
    const uint4* cp = reinterpret_cast<const uint4*>(
        ckvT + (((size_t)(b * NSC + c0 + c) * RANKC) + rg * 128 + rloc) * 64 + shalf);
    ctreg[0] = cp[0]; ctreg[1] = cp[1]; ctreg[2] = cp[2]; ctreg[3] = cp[3];
    const uint4* pp = reinterpret_cast<const uint4*>(
        Pg + ((size_t)(b * NSC + c0 + c) * NQ + prow) * 64 + pseg);
    plreg[0] = pp[0]; plreg[1] = pp[1];
  };
  auto writec = [&]() {
    uint4* d = reinterpret_cast<uint4*>(&CT[rloc * LP + shalf]);
    d[0] = ctreg[0]; d[1] = ctreg[1]; d[2] = ctreg[2]; d[3] = ctreg[3];
    uint4* p = reinterpret_cast<uint4*>(&PLs[prow * LP + pseg]);
    p[0] = plreg[0]; p[1] = plreg[1];
  };

  f32x4 OACC[8];
  #pragma unroll
  for (int nt = 0; nt < 8; ++nt) OACC[nt] = (f32x4){0.f, 0.f, 0.f, 0.f};

  loadc(0);
  __syncthreads();    // wlds visible
  for (int c = 0; c < nc; ++c) {
    writec();
    __syncthreads();
    if (c + 1 < nc) loadc(c + 1);
    const bf16x8 pa0 = *reinterpret_cast<const bf16x8*>(&PLs[(m0 + lm) * LP + lg * 8]);
    const bf16x8 pa1 = *reinterpret_cast<const bf16x8*>(&PLs[(m0 + lm) * LP + 32 + lg * 8]);
    f32x4 a2[8];
    #pragma unroll
    for (int nt = 0; nt < 8; ++nt) a2[nt] = (f32x4){0.f, 0.f, 0.f, 0.f};
    #pragma unroll
    for (int nt = 0; nt < 8; ++nt) {
      const bf16x8 b0 = *reinterpret_cast<const bf16x8*>(&CT[(nt * 16 + lm) * LP + lg * 8]);
      const bf16x8 b1 = *reinterpret_cast<const bf16x8*>(&CT[(nt * 16 + lm) * LP + 32 + lg * 8]);
      a2[nt] = __builtin_amdgcn_mfma_f32_16x16x32_bf16(pa0, b0, a2[nt], 0, 0, 0);
      a2[nt] = __builtin_amdgcn_mfma_f32_16x16x32_bf16(pa1, b1, a2[nt], 0, 0, 0);
    }
    const f32x4 w = (f32x4){wlds[c][m0 + lg * 4 + 0], wlds[c][m0 + lg * 4 + 1],
                            wlds[c][m0 + lg * 4 + 2], wlds[c][m0 + lg * 4 + 3]};
    #pragma unroll
    for (int nt = 0; nt < 8; ++nt) OACC[nt] += w * a2[nt];
    __syncthreads();
  }

  const size_t obase = ((size_t)(b * NG + g) * NQ) * RANKC;
  #pragma unroll
  for (int nt = 0; nt < 8; ++nt)
    #pragma unroll
    for (int reg = 0; reg < 4; ++reg)
      olat[obase + (size_t)(m0 + lg * 4 + reg) * RANKC + rg * 128 + nt * 16 + lm] = OACC[nt][reg];
}

// ---------------- fused combine (17 fp32 group partials) + out_head epilogue
__global__ __launch_bounds__(512) void k_combF(const float* __restrict__ mlg,
                                               const float* __restrict__ olat,
                                               const float* __restrict__ wup,
                                               float* __restrict__ ohead) {
  __shared__ float wrow[4][20];
  __shared__ float att_lds[4][516];
  const int h = blockIdx.x, b = blockIdx.y;
  const int tid = threadIdx.x;
  const int wave = tid >> 6;
  const int i = wave >> 1;
  const int rhalf = wave & 1;
  const int rl = tid & 63;
  const int qi = h * TT + i;
  float m1 = -1e30f, l1 = 0.f;
  if (rl < NG) {
    const size_t base = (((size_t)b * NG + rl) * NQ + qi) * 2;
    m1 = mlg[base]; l1 = mlg[base + 1];
  }
  float M = m1;
  #pragma unroll
  for (int off = 1; off < 64; off <<= 1) M = fmaxf(M, __shfl_xor(M, off));
  float L = (rl < NG) ? l1 * __expf(m1 - M) : 0.f;
  #pragma unroll
  for (int off = 1; off < 64; off <<= 1) L += __shfl_xor(L, off);
  const float invL = 1.0f / L;
  if (rl < NG) wrow[i][rl] = __expf(m1 - M) * invL;
  __syncthreads();
  const int r0 = rhalf * 256 + rl * 4;
  float o0 = 0.f, o1 = 0.f, o2 = 0.f, o3 = 0.f;
  for (int c = 0; c < NG; ++c) {
    const float w = wrow[i][c];
    const float4 v = *reinterpret_cast<const float4*>(
        olat + (((size_t)b * NG + c) * NQ + qi) * RANKC + r0);
    o0 = fmaf(v.x, w, o0); o1 = fmaf(v.y, w, o1);
    o2 = fmaf(v.z, w, o2); o3 = fmaf(v.w, w, o3);
  }
  *reinterpret_cast<float4*>(&att_lds[i][r0]) = make_float4(o0, o1, o2, o3);
  __syncthreads();
  const int col = tid & 127;
  const int t = tid >> 7;
  float acc = 0.f;
  #pragma unroll 8
  for (int r = 0; r < RANKC; ++r)
    acc = fmaf(att_lds[t][r], wup[(size_t)r * HD + h * DDIM + col], acc);
  ohead[(size_t)(b * TT + t) * HD + h * DDIM + col] = acc;
}

extern "C" void kernel_launch(void* const* d_in, const int* in_sizes, int n_in,
                              void* d_out, int out_size, void* d_ws, size_t ws_size,
                              hipStream_t stream) {
  const float* x     = (const float*)d_in[0];
  const float* cckv  = (const float*)d_in[1];
  const float* ckr   = (const float*)d_in[2];
  const float* w_q   = (const float*)d_in[3];
  const float* w_qr  = (const float*)d_in[4];
  const float* w_kvd = (const float*)d_in[5];
  const float* w_kvu = (const float*)d_in[6];
  const float* w_kr  = (const float*)d_in[7];
  const float* w_out = (const float*)d_in[8];
  float* out = (float*)d_out;
  float* ws = (float*)d_ws;

  size_t off = 0;
  float* act      = ws + off; off += 32ull * NACT;                  // 114688
  ushortT* qlat   = (ushortT*)(ws + off); off += 131072;
  float* qrope    = ws + off; off += 32768;
  float* ckvn     = ws + off; off += 16384;
  float* krn      = ws + off; off += 32768;
  float* mlb      = ws + off; off += (size_t)BB * NSC * NQ * 2;     // 66560
  float* mlgb     = ws + off; off += (size_t)BB * NG * NQ * 2;      // 17408
  float* ohead    = ws + off; off += 65536;
  __half* rsb     = (__half*)(ws + off); off += 1064960;
  ushortT* ckvT   = (ushortT*)(ws + off); off += 8519680;
  ushortT* Pgb    = (ushortT*)(ws + off); off += 1064960;           // 520*64*64 bf16
  // region B (time-shared): part0 -> olat(fp32, 17 groups) -> part3
  float* regB  = ws + off;
  float* part0 = regB;                 // 1,835,008 f
  float* olat  = regB;                 // 8*17*64*512 = 4,456,448 f (max)
  float* part3 = regB;                 // 1,048,576 f

  k_front<<<dim3(968), 256, 0, stream>>>(x, w_q, w_qr, w_kvd, w_kr, cckv, part0, ckvT);
  k_reduce<<<dim3(448), 256, 0, stream>>>(part0, act, 32 * NACT, 16);
  k_qlatrope<<<dim3(256), 256, 0, stream>>>(act, w_kvu, qlat, qrope, ckvn, krn, ckvT);
  k_rscore<<<dim3(128, 9), 256, 0, stream>>>(ckr, krn, qrope, rsb);

  k_score<<<dim3(BB, NSC), 256, 0, stream>>>(cckv, ckvn, qlat, rsb, mlb, Pgb);
  k_pv<<<dim3(BB, NG, 4), 256, 0, stream>>>(ckvT, Pgb, mlb, olat, mlgb);

  k_combF<<<dim3(16, 8), 512, 0, stream>>>(mlgb, olat, w_kvu, ohead);
  k_proj<<<dim3(16, 16), 256, 0, stream>>>(ohead, w_out, part3, 2048, 2048, 0);
  k_reduce<<<dim3(256), 256, 0, stream>>>(part3, out, 32 * HD, 16);
}

// Round 7
// 213.007 us; speedup vs baseline: 1.1342x; 1.1069x over previous
//
#include <hip/hip_runtime.h>
#include <hip/hip_fp16.h>
#include <cmath>

#define BB 8
#define TT 4
#define HH 16
#define DDIM 128
#define RRDIM 64
#define CCDIM 64
#define RANKC 512
#define DMODEL 2048
#define S0C 4096
#define NQ 64      // H*T queries per batch
#define HD 2048    // H*D
#define NACT 3584
#define NSC 65     // 64 cache chunks of 64 + 1 new-token chunk
#define NG 17      // 16 groups of 4 chunks + 1 new-token group
#define SPAD 4160
#define SCALE_ATT 0.08838834764831845f  // 1/sqrt(128)

typedef __attribute__((ext_vector_type(8))) short bf16x8;
typedef __attribute__((ext_vector_type(4))) float f32x4;
typedef unsigned short ushortT;

#define AIDX(row, kk) ((row)*132 + (((row)>>2)<<2) + (kk))

static __device__ __forceinline__ unsigned short f2bf(float x) {
  unsigned u = __float_as_uint(x);
  u += 0x7FFFu + ((u >> 16) & 1u);
  return (unsigned short)(u >> 16);
}
static __device__ __forceinline__ unsigned pk2(float a, float b) {
  return (unsigned)f2bf(a) | ((unsigned)f2bf(b) << 16);
}

// ---------------- L0: fused front projections + c_kv bf16 copies (row-major ckvB + transposed ckvT)
// blocks [0,448): proj4; [448,960): cvt/transpose; [960,968): zero ckvB ch64; [968,976): zero ckvT ch64
__global__ __launch_bounds__(256) void k_front(const float* __restrict__ A,
                                               const float* __restrict__ w0,
                                               const float* __restrict__ w1,
                                               const float* __restrict__ w2,
                                               const float* __restrict__ w3,
                                               const float* __restrict__ cckv,
                                               float* __restrict__ part,
                                               ushortT* __restrict__ ckvB,
                                               ushortT* __restrict__ ckvT) {
  __shared__ float shf[4352];
  const int tid = threadIdx.x;
  const int bx = blockIdx.x;
  if (bx < 448) {
    const int cb = bx % 28;
    const int k0 = (bx / 28) * 128;
    const float* W; int N, lc0, off;
    if (cb < 8)       { W = w0; N = 1024; lc0 = cb * 128;        off = 0; }
    else if (cb < 16) { W = w1; N = 1024; lc0 = (cb - 8) * 128;  off = 1024; }
    else if (cb < 20) { W = w2; N = 512;  lc0 = (cb - 16) * 128; off = 2048; }
    else              { W = w3; N = 1024; lc0 = (cb - 20) * 128; off = 2560; }
    {
      const int row = tid >> 3;
      const int kseg = (tid & 7) * 16;
      const float4* s4 = reinterpret_cast<const float4*>(A + (size_t)row * DMODEL + k0 + kseg);
      float4 v0 = s4[0], v1 = s4[1], v2 = s4[2], v3 = s4[3];
      *reinterpret_cast<float4*>(&shf[AIDX(row, kseg)])      = v0;
      *reinterpret_cast<float4*>(&shf[AIDX(row, kseg + 4)])  = v1;
      *reinterpret_cast<float4*>(&shf[AIDX(row, kseg + 8)])  = v2;
      *reinterpret_cast<float4*>(&shf[AIDX(row, kseg + 12)]) = v3;
    }
    __syncthreads();
    const int cg = tid & 31;
    const int rg = tid >> 5;
    float acc[4][4];
    #pragma unroll
    for (int r = 0; r < 4; ++r)
      #pragma unroll
      for (int c = 0; c < 4; ++c) acc[r][c] = 0.f;
    #pragma unroll 4
    for (int kk = 0; kk < 128; ++kk) {
      const float4 w4 = *reinterpret_cast<const float4*>(W + (size_t)(k0 + kk) * N + lc0 + cg * 4);
      const float wv[4] = {w4.x, w4.y, w4.z, w4.w};
      #pragma unroll
      for (int r = 0; r < 4; ++r) {
        const float av = shf[AIDX(rg * 4 + r, kk)];
        #pragma unroll
        for (int c = 0; c < 4; ++c) acc[r][c] = fmaf(av, wv[c], acc[r][c]);
      }
    }
    #pragma unroll
    for (int r = 0; r < 4; ++r) {
      float4 o = make_float4(acc[r][0], acc[r][1], acc[r][2], acc[r][3]);
      *reinterpret_cast<float4*>(part + ((size_t)(bx / 28) * 32 + rg * 4 + r) * NACT + off + lc0 + cg * 4) = o;
    }
  } else if (bx < 960) {
    ushortT* tlds = reinterpret_cast<ushortT*>(shf);   // [64 s][136]
    const int idx = bx - 448;
    const int b = idx >> 6, c = idx & 63;
    const float* src = cckv + ((size_t)b * S0C + c * 64) * RANKC;
    ushortT* dstB = ckvB + ((size_t)(b * NSC + c) * 64) * RANKC;
    ushortT* dstT = ckvT + ((size_t)(b * NSC + c) * RANKC) * 64;
    const int s = tid >> 2, rq = tid & 3;
    const int rloc = tid >> 1, shalf = (tid & 1) * 32;
    for (int slab = 0; slab < 4; ++slab) {
      const int r0 = slab * 128;
      #pragma unroll
      for (int i = 0; i < 8; ++i) {
        const float4 v = *reinterpret_cast<const float4*>(src + (size_t)s * RANKC + r0 + rq * 32 + i * 4);
        const uint2 pk = make_uint2(pk2(v.x, v.y), pk2(v.z, v.w));
        *reinterpret_cast<uint2*>(&tlds[s * 136 + rq * 32 + i * 4]) = pk;
        *reinterpret_cast<uint2*>(&dstB[(size_t)s * RANKC + r0 + rq * 32 + i * 4]) = pk;
      }
      __syncthreads();
      unsigned pkv[16];
      #pragma unroll
      for (int k = 0; k < 16; ++k) {
        const unsigned t0 = tlds[(shalf + 2 * k)     * 136 + rloc];
        const unsigned t1 = tlds[(shalf + 2 * k + 1) * 136 + rloc];
        pkv[k] = t0 | (t1 << 16);
      }
      uint4* d = reinterpret_cast<uint4*>(dstT + ((size_t)(r0 + rloc)) * 64 + shalf);
      d[0] = make_uint4(pkv[0], pkv[1], pkv[2], pkv[3]);
      d[1] = make_uint4(pkv[4], pkv[5], pkv[6], pkv[7]);
      d[2] = make_uint4(pkv[8], pkv[9], pkv[10], pkv[11]);
      d[3] = make_uint4(pkv[12], pkv[13], pkv[14], pkv[15]);
      __syncthreads();
    }
  } else if (bx < 968) {
    const int b = bx - 960;
    uint4* p = reinterpret_cast<uint4*>(ckvB + ((size_t)(b * NSC + 64) * 64) * RANKC);
    const uint4 z = make_uint4(0, 0, 0, 0);
    for (int i = tid; i < 4096; i += 256) p[i] = z;
  } else {
    const int b = bx - 968;
    uint4* p = reinterpret_cast<uint4*>(ckvT + ((size_t)(b * NSC + 64) * RANKC) * 64);
    const uint4 z = make_uint4(0, 0, 0, 0);
    for (int i = tid; i < 4096; i += 256) p[i] = z;
  }
}

// ---------------- plain skinny GEMM for the w_out epilogue
__global__ __launch_bounds__(256) void k_proj(const float* __restrict__ A,
                                              const float* __restrict__ W,
                                              float* __restrict__ part,
                                              int N, int NTOT, int coloff) {
  __shared__ float a_lds[4352];
  const int tid = threadIdx.x;
  const int c0 = blockIdx.x * 128;
  const int k0 = blockIdx.y * 128;
  {
    const int row = tid >> 3;
    const int kseg = (tid & 7) * 16;
    const float4* s4 = reinterpret_cast<const float4*>(A + (size_t)row * DMODEL + k0 + kseg);
    float4 v0 = s4[0], v1 = s4[1], v2 = s4[2], v3 = s4[3];
    *reinterpret_cast<float4*>(&a_lds[AIDX(row, kseg)])      = v0;
    *reinterpret_cast<float4*>(&a_lds[AIDX(row, kseg + 4)])  = v1;
    *reinterpret_cast<float4*>(&a_lds[AIDX(row, kseg + 8)])  = v2;
    *reinterpret_cast<float4*>(&a_lds[AIDX(row, kseg + 12)]) = v3;
  }
  __syncthreads();
  const int cg = tid & 31;
  const int rg = tid >> 5;
  float acc[4][4];
  #pragma unroll
  for (int r = 0; r < 4; ++r)
    #pragma unroll
    for (int c = 0; c < 4; ++c) acc[r][c] = 0.f;
  #pragma unroll 4
  for (int kk = 0; kk < 128; ++kk) {
    const float4 w4 = *reinterpret_cast<const float4*>(W + (size_t)(k0 + kk) * N + c0 + cg * 4);
    const float wv[4] = {w4.x, w4.y, w4.z, w4.w};
    #pragma unroll
    for (int r = 0; r < 4; ++r) {
      const float av = a_lds[AIDX(rg * 4 + r, kk)];
      #pragma unroll
      for (int c = 0; c < 4; ++c) acc[r][c] = fmaf(av, wv[c], acc[r][c]);
    }
  }
  #pragma unroll
  for (int r = 0; r < 4; ++r) {
    float4 o = make_float4(acc[r][0], acc[r][1], acc[r][2], acc[r][3]);
    *reinterpret_cast<float4*>(part + ((size_t)blockIdx.y * 32 + rg * 4 + r) * NTOT + coloff + c0 + cg * 4) = o;
  }
}

// ---------------- reduce K-splits
__global__ __launch_bounds__(256) void k_reduce(const float* __restrict__ part,
                                                float* __restrict__ out, int total, int nsplit) {
  int g = blockIdx.x * 256 + threadIdx.x;
  if (g >= total) return;
  float s = 0.f;
  #pragma unroll 4
  for (int c = 0; c < nsplit; ++c) s += part[(size_t)c * total + g];
  out[g] = s;
}

// ---------------- fused q_lat(bf16) + RoPE + c_kv_new bf16 into ckvB/ckvT chunk 64
__global__ __launch_bounds__(256) void k_qlatrope(const float* __restrict__ act,
                                                  const float* __restrict__ wup,
                                                  ushortT* __restrict__ qlat,
                                                  float* __restrict__ qrope,
                                                  float* __restrict__ krn,
                                                  ushortT* __restrict__ ckvB,
                                                  ushortT* __restrict__ ckvT) {
  __shared__ float wt[64 * 132];
  __shared__ float a_s[32 * 68];
  const int tid = threadIdx.x;
  const int bx = blockIdx.x;
  if (bx < 64) {
    const int h = bx & 15;
    const int r0 = (bx >> 4) * 128;
    {
      const int r = tid >> 1;
      const int cseg = (tid & 1) * 32;
      const float* src = wup + (size_t)(r0 + r) * HD + h * DDIM + cseg;
      #pragma unroll
      for (int u = 0; u < 8; ++u) {
        const float4 v = *reinterpret_cast<const float4*>(src + u * 4);
        wt[(cseg + u * 4 + 0) * 132 + r] = v.x;
        wt[(cseg + u * 4 + 1) * 132 + r] = v.y;
        wt[(cseg + u * 4 + 2) * 132 + r] = v.z;
        wt[(cseg + u * 4 + 3) * 132 + r] = v.w;
      }
    }
    {
      const int bt = tid >> 3;
      const int cseg = (tid & 7) * 8;
      const float4* s4 = reinterpret_cast<const float4*>(act + (size_t)bt * NACT + h * CCDIM + cseg);
      float4 v0 = s4[0], v1 = s4[1];
      *reinterpret_cast<float4*>(&a_s[bt * 68 + cseg])     = v0;
      *reinterpret_cast<float4*>(&a_s[bt * 68 + cseg + 4]) = v1;
    }
    __syncthreads();
    const int r = tid & 127;
    const int bth = tid >> 7;
    float acc[16];
    #pragma unroll
    for (int i = 0; i < 16; ++i) acc[i] = 0.f;
    #pragma unroll 8
    for (int c = 0; c < 64; ++c) {
      const float wv = wt[c * 132 + r];
      #pragma unroll
      for (int i = 0; i < 16; ++i)
        acc[i] = fmaf(a_s[(bth * 16 + i) * 68 + c], wv, acc[i]);
    }
    #pragma unroll
    for (int i = 0; i < 16; ++i) {
      const int bt = bth * 16 + i;
      const int b = bt >> 2, t = bt & 3;
      qlat[((size_t)(b * NQ) + h * TT + t) * RANKC + r0 + r] = f2bf(acc[i]);
    }
    return;
  }
  int g = (bx - 64) * 256 + tid;
  if (g < BB * TT * HH * 32) {                  // q_rope pairs
    const int hj = g & 31;
    const int h = (g >> 5) & 15;
    const int t = (g >> 9) & 3;
    const int b = g >> 11;
    const float* arow = act + (size_t)(b * TT + t) * NACT + 1024 + h * RRDIM;
    const float x1 = arow[hj], x2 = arow[hj + 32];
    const double fr = (double)(S0C + t) * pow(10000.0, -(double)hj / 32.0);
    const float cs = (float)cos(fr), sn = (float)sin(fr);
    const int qi = h * TT + t;
    qrope[((size_t)b * NQ + qi) * RRDIM + hj]      = x1 * cs - x2 * sn;
    qrope[((size_t)b * NQ + qi) * RRDIM + hj + 32] = x1 * sn + x2 * cs;
    return;
  }
  g -= BB * TT * HH * 32;
  if (g < BB * TT * HH * 32) {                  // k_rope_new pairs
    const int hj = g & 31;
    const int h = (g >> 5) & 15;
    const int t = (g >> 9) & 3;
    const int b = g >> 11;
    const float* arow = act + (size_t)(b * TT + t) * NACT + 2560 + h * RRDIM;
    const float x1 = arow[hj], x2 = arow[hj + 32];
    const double fr = (double)(S0C + t) * pow(10000.0, -(double)hj / 32.0);
    const float cs = (float)cos(fr), sn = (float)sin(fr);
    krn[((size_t)(b * TT + t) * HH + h) * RRDIM + hj]      = x1 * cs - x2 * sn;
    krn[((size_t)(b * TT + t) * HH + h) * RRDIM + hj + 32] = x1 * sn + x2 * cs;
    return;
  }
  g -= BB * TT * HH * 32;
  if (g < BB * TT * RANKC) {                    // c_kv_new bf16 into ckvB / ckvT chunk 64
    const int r = g & 511;
    const int bt = g >> 9;
    const int b = bt >> 2, t = bt & 3;
    const ushortT bv = f2bf(act[(size_t)bt * NACT + 2048 + r]);
    ckvB[(((size_t)(b * NSC + 64) * 64) + t) * RANKC + r] = bv;
    ckvT[(((size_t)(b * NSC + 64) * RANKC) + r) * 64 + t] = bv;
  }
}

// ---------------- rope scores (pre-scaled, fp16)
__global__ __launch_bounds__(256) void k_rscore(const float* __restrict__ cache_kr,
                                                const float* __restrict__ krn,
                                                const float* __restrict__ qrope,
                                                __half* __restrict__ rs) {
  const int bh = blockIdx.x;
  const int b = bh >> 4, h = bh & 15;
  const int tid = threadIdx.x;
  const int ql = tid & 3;
  float4 qf[4][4];
  const float* qrb = qrope + ((size_t)b * NQ + h * TT) * RRDIM;
  #pragma unroll
  for (int t = 0; t < 4; ++t)
    #pragma unroll
    for (int u = 0; u < 4; ++u)
      qf[t][u] = *reinterpret_cast<const float4*>(qrb + t * RRDIM + ql * 16 + u * 4);
  const int s0 = blockIdx.y * 512;
  #pragma unroll 1
  for (int pass = 0; pass < 8; ++pass) {
    const int s = s0 + pass * 64 + (tid >> 2);
    if (s < 4100) {
      const float* krow = (s < S0C)
        ? cache_kr + (((size_t)b * S0C + s) * HH + h) * RRDIM
        : krn + (((size_t)b * TT + (s - S0C)) * HH + h) * RRDIM;
      float p[4] = {0.f, 0.f, 0.f, 0.f};
      #pragma unroll
      for (int u = 0; u < 4; ++u) {
        const float4 kv = *reinterpret_cast<const float4*>(krow + ql * 16 + u * 4);
        #pragma unroll
        for (int t = 0; t < 4; ++t) {
          p[t] += kv.x * qf[t][u].x + kv.y * qf[t][u].y
                + kv.z * qf[t][u].z + kv.w * qf[t][u].w;
        }
      }
      #pragma unroll
      for (int t = 0; t < 4; ++t) {
        p[t] += __shfl_xor(p[t], 1, 4);
        p[t] += __shfl_xor(p[t], 2, 4);
      }
      rs[((size_t)bh * 4 + ql) * SPAD + s] = __float2half(p[ql] * SCALE_ATT);
    }
  }
}

// ---------------- k_score: direct-global MFMA, Q in registers, one barrier
// grid (8 b, 65 chunks, 2 q-halves), 128 thr = 2 waves; wave covers 16 q x 64 s
__global__ __launch_bounds__(128) void k_score(
    const ushortT* __restrict__ ckvB, const ushortT* __restrict__ qlat,
    const __half* __restrict__ rs, float* __restrict__ ml,
    ushortT* __restrict__ Pg) {
  __shared__ ushortT PL[2][16 * 72];
  const int tid = threadIdx.x;
  const int wv = tid >> 6;
  const int lane = tid & 63;
  const int lm = lane & 15, lg = lane >> 4;
  const int b = blockIdx.x, chunk = blockIdx.y;
  const int qbase = blockIdx.z * 32 + wv * 16;
  const int scnt = (chunk < 64) ? 64 : TT;

  // Q fragments in registers: row qbase+lm, k = ks*32 + lg*8
  const ushortT* qrow = qlat + ((size_t)b * NQ + qbase + lm) * RANKC + lg * 8;
  bf16x8 qa[16];
  #pragma unroll
  for (int ks = 0; ks < 16; ++ks)
    qa[ks] = *reinterpret_cast<const bf16x8*>(qrow + ks * 32);

  // B fragments straight from global ckvB (64B-segment pattern)
  const ushortT* bbase = ckvB + ((size_t)(b * NSC + chunk) * 64) * RANKC;
  f32x4 acc[4];
  #pragma unroll
  for (int st = 0; st < 4; ++st) acc[st] = (f32x4){0.f, 0.f, 0.f, 0.f};
  #pragma unroll
  for (int ks = 0; ks < 16; ++ks) {
    #pragma unroll
    for (int st = 0; st < 4; ++st) {
      const bf16x8 bf = *reinterpret_cast<const bf16x8*>(
          bbase + (size_t)(st * 16 + lm) * RANKC + ks * 32 + lg * 8);
      acc[st] = __builtin_amdgcn_mfma_f32_16x16x32_bf16(qa[ks], bf, acc[st], 0, 0, 0);
    }
  }

  // rope + softmax; D-frag: s = st*16+lm, q = qbase + lg*4 + reg
  #pragma unroll
  for (int reg = 0; reg < 4; ++reg) {
    const int qi = qbase + lg * 4 + reg;
    const __half* rp = rs + (((size_t)(b * HH) + (qi >> 2)) * TT + (qi & 3)) * SPAD + chunk * 64;
    float vvv[4];
    float mx = -1e30f;
    #pragma unroll
    for (int st = 0; st < 4; ++st) {
      const int sl = st * 16 + lm;
      const float val = (sl < scnt)
          ? fmaf(acc[st][reg], SCALE_ATT, __half2float(rp[sl]))
          : -1e30f;
      vvv[st] = val;
      mx = fmaxf(mx, val);
    }
    #pragma unroll
    for (int off = 1; off < 16; off <<= 1) mx = fmaxf(mx, __shfl_xor(mx, off, 16));
    float sum = 0.f;
    #pragma unroll
    for (int st = 0; st < 4; ++st) {
      const float p = __expf(vvv[st] - mx);
      vvv[st] = p;
      sum += p;
    }
    #pragma unroll
    for (int off = 1; off < 16; off <<= 1) sum += __shfl_xor(sum, off, 16);
    #pragma unroll
    for (int st = 0; st < 4; ++st)
      PL[wv][(lg * 4 + reg) * 72 + st * 16 + lm] = f2bf(vvv[st]);
    if (lm == 0) {
      const size_t mb = (((size_t)b * NSC + chunk) * NQ + qi) * 2;
      ml[mb] = mx; ml[mb + 1] = sum;
    }
  }
  __syncthreads();
  // P~ store: each wave stores its own 16 rows (128B each)
  {
    const int row = lane >> 2, seg = (lane & 3) * 16;
    const uint4* sp = reinterpret_cast<const uint4*>(&PL[wv][row * 72 + seg]);
    uint4* dp = reinterpret_cast<uint4*>(
        Pg + ((size_t)(b * NSC + chunk) * NQ + qbase + row) * 64 + seg);
    dp[0] = sp[0]; dp[1] = sp[1];
  }
}

// ---------------- k_pv: zero-LDS zero-barrier group-accumulated PV
// grid (8 b, 17 g, 8 = rg*2+qh), 128 thr = 2 waves; wave covers 16 q x 128 r, 4 chunks
__global__ __launch_bounds__(128) void k_pv(
    const ushortT* __restrict__ ckvT, const ushortT* __restrict__ Pg,
    const float* __restrict__ ml, float* __restrict__ olat,
    float* __restrict__ mlg) {
  const int tid = threadIdx.x;
  const int wv = tid >> 6;
  const int lane = tid & 63;
  const int lm = lane & 15, lg = lane >> 4;
  const int b = blockIdx.x, g = blockIdx.y;
  const int rg = blockIdx.z >> 1, qh = blockIdx.z & 1;
  const int qbase = qh * 32 + wv * 16;
  const int nc = (g < 16) ? 4 : 1;
  const int c0 = (g < 16) ? g * 4 : 64;

  // per-lane (c = lg, q = qbase + lm) stats; reduce over lg
  float m_cl = -1e30f, l_cl = 0.f;
  if (lg < nc) {
    const size_t mb = (((size_t)b * NSC + c0 + lg) * NQ + qbase + lm) * 2;
    m_cl = ml[mb]; l_cl = ml[mb + 1];
  }
  float mg = fmaxf(m_cl, __shfl_xor(m_cl, 16));
  mg = fmaxf(mg, __shfl_xor(mg, 32));
  const float wgt = (lg < nc) ? __expf(m_cl - mg) : 0.f;
  float la = l_cl * wgt;
  la += __shfl_xor(la, 16);
  la += __shfl_xor(la, 32);
  if (rg == 0 && lg == 0) {
    const size_t gb = (((size_t)b * NG + g) * NQ + qbase + lm) * 2;
    mlg[gb] = mg; mlg[gb + 1] = la;
  }
  // redistribute weights to D-frag rows: wf[c][reg] = w(q = qbase+lg*4+reg, c)
  float wf[4][4];
  #pragma unroll
  for (int c = 0; c < 4; ++c)
    #pragma unroll
    for (int reg = 0; reg < 4; ++reg)
      wf[c][reg] = __shfl(wgt, c * 16 + lg * 4 + reg);

  f32x4 OACC[8];
  #pragma unroll
  for (int nt = 0; nt < 8; ++nt) OACC[nt] = (f32x4){0.f, 0.f, 0.f, 0.f};

  for (int c = 0; c < nc; ++c) {
    const ushortT* pb = Pg + ((size_t)(b * NSC + c0 + c) * NQ + qbase + lm) * 64 + lg * 8;
    const bf16x8 pa0 = *reinterpret_cast<const bf16x8*>(pb);
    const bf16x8 pa1 = *reinterpret_cast<const bf16x8*>(pb + 32);
    const ushortT* vb = ckvT + (((size_t)(b * NSC + c0 + c) * RANKC) + rg * 128 + lm) * 64 + lg * 8;
    f32x4 a2[8];
    #pragma unroll
    for (int nt = 0; nt < 8; ++nt) a2[nt] = (f32x4){0.f, 0.f, 0.f, 0.f};
    #pragma unroll
    for (int nt = 0; nt < 8; ++nt) {
      const bf16x8 b0 = *reinterpret_cast<const bf16x8*>(vb + (size_t)nt * 16 * 64);
      const bf16x8 b1 = *reinterpret_cast<const bf16x8*>(vb + (size_t)nt * 16 * 64 + 32);
      a2[nt] = __builtin_amdgcn_mfma_f32_16x16x32_bf16(pa0, b0, a2[nt], 0, 0, 0);
      a2[nt] = __builtin_amdgcn_mfma_f32_16x16x32_bf16(pa1, b1, a2[nt], 0, 0, 0);
    }
    const f32x4 wv4 = {wf[c][0], wf[c][1], wf[c][2], wf[c][3]};
    #pragma unroll
    for (int nt = 0; nt < 8; ++nt) OACC[nt] += wv4 * a2[nt];
  }

  const size_t obase = ((size_t)(b * NG + g) * NQ) * RANKC;
  #pragma unroll
  for (int nt = 0; nt < 8; ++nt)
    #pragma unroll
    for (int reg = 0; reg < 4; ++reg)
      olat[obase + (size_t)(qbase + lg * 4 + reg) * RANKC + rg * 128 + nt * 16 + lm] = OACC[nt][reg];
}

// ---------------- fused combine (17 fp32 group partials) + out_head epilogue
__global__ __launch_bounds__(512) void k_combF(const float* __restrict__ mlg,
                                               const float* __restrict__ olat,
                                               const float* __restrict__ wup,
                                               float* __restrict__ ohead) {
  __shared__ float wrow[4][20];
  __shared__ float att_lds[4][516];
  const int h = blockIdx.x, b = blockIdx.y;
  const int tid = threadIdx.x;
  const int wave = tid >> 6;
  const int i = wave >> 1;
  const int rhalf = wave & 1;
  const int rl = tid & 63;
  const int qi = h * TT + i;
  float m1 = -1e30f, l1 = 0.f;
  if (rl < NG) {
    const size_t base = (((size_t)b * NG + rl) * NQ + qi) * 2;
    m1 = mlg[base]; l1 = mlg[base + 1];
  }
  float M = m1;
  #pragma unroll
  for (int off = 1; off < 64; off <<= 1) M = fmaxf(M, __shfl_xor(M, off));
  float L = (rl < NG) ? l1 * __expf(m1 - M) : 0.f;
  #pragma unroll
  for (int off = 1; off < 64; off <<= 1) L += __shfl_xor(L, off);
  const float invL = 1.0f / L;
  if (rl < NG) wrow[i][rl] = __expf(m1 - M) * invL;
  __syncthreads();
  const int r0 = rhalf * 256 + rl * 4;
  float o0 = 0.f, o1 = 0.f, o2 = 0.f, o3 = 0.f;
  for (int c = 0; c < NG; ++c) {
    const float w = wrow[i][c];
    const float4 v = *reinterpret_cast<const float4*>(
        olat + (((size_t)b * NG + c) * NQ + qi) * RANKC + r0);
    o0 = fmaf(v.x, w, o0); o1 = fmaf(v.y, w, o1);
    o2 = fmaf(v.z, w, o2); o3 = fmaf(v.w, w, o3);
  }
  *reinterpret_cast<float4*>(&att_lds[i][r0]) = make_float4(o0, o1, o2, o3);
  __syncthreads();
  const int col = tid & 127;
  const int t = tid >> 7;
  float acc = 0.f;
  #pragma unroll 8
  for (int r = 0; r < RANKC; ++r)
    acc = fmaf(att_lds[t][r], wup[(size_t)r * HD + h * DDIM + col], acc);
  ohead[(size_t)(b * TT + t) * HD + h * DDIM + col] = acc;
}

extern "C" void kernel_launch(void* const* d_in, const int* in_sizes, int n_in,
                              void* d_out, int out_size, void* d_ws, size_t ws_size,
                              hipStream_t stream) {
  const float* x     = (const float*)d_in[0];
  const float* cckv  = (const float*)d_in[1];
  const float* ckr   = (const float*)d_in[2];
  const float* w_q   = (const float*)d_in[3];
  const float* w_qr  = (const float*)d_in[4];
  const float* w_kvd = (const float*)d_in[5];
  const float* w_kvu = (const float*)d_in[6];
  const float* w_kr  = (const float*)d_in[7];
  const float* w_out = (const float*)d_in[8];
  float* out = (float*)d_out;
  float* ws = (float*)d_ws;

  size_t off = 0;
  float* act      = ws + off; off += 32ull * NACT;                  // 114688
  ushortT* qlat   = (ushortT*)(ws + off); off += 131072;
  float* qrope    = ws + off; off += 32768;
  float* krn      = ws + off; off += 32768;
  float* mlb      = ws + off; off += (size_t)BB * NSC * NQ * 2;     // 66560
  float* mlgb     = ws + off; off += (size_t)BB * NG * NQ * 2;      // 17408
  float* ohead    = ws + off; off += 65536;
  __half* rsb     = (__half*)(ws + off); off += 1064960;            // 512*4160 fp16
  ushortT* ckvB   = (ushortT*)(ws + off); off += 8519680;           // 8*65*64*512 bf16
  ushortT* ckvT   = (ushortT*)(ws + off); off += 8519680;
  ushortT* Pgb    = (ushortT*)(ws + off); off += 1064960;
  // region B (time-shared): part0 -> olat(fp32) -> part3
  float* regB  = ws + off;
  float* part0 = regB;
  float* olat  = regB;                  // 8*17*64*512 = 4,456,448 f (max)
  float* part3 = regB;

  k_front<<<dim3(976), 256, 0, stream>>>(x, w_q, w_qr, w_kvd, w_kr, cckv, part0, ckvB, ckvT);
  k_reduce<<<dim3(448), 256, 0, stream>>>(part0, act, 32 * NACT, 16);
  k_qlatrope<<<dim3(256), 256, 0, stream>>>(act, w_kvu, qlat, qrope, krn, ckvB, ckvT);
  k_rscore<<<dim3(128, 9), 256, 0, stream>>>(ckr, krn, qrope, rsb);

  k_score<<<dim3(BB, NSC, 2), 128, 0, stream>>>(ckvB, qlat, rsb, mlb, Pgb);
  k_pv<<<dim3(BB, NG, 8), 128, 0, stream>>>(ckvT, Pgb, mlb, olat, mlgb);

  k_combF<<<dim3(16, 8), 512, 0, stream>>>(mlgb, olat, w_kvu, ohead);
  k_proj<<<dim3(16, 16), 256, 0, stream>>>(ohead, w_out, part3, 2048, 2048, 0);
  k_reduce<<<dim3(256), 256, 0, stream>>>(part3, out, 32 * HD, 16);
}